// Round 9
// baseline (192.687 us; speedup 1.0000x reference)
//
#include <hip/hip_runtime.h>

#define N_NODES 100000
#define N_EDGES 1600000
#define NFEAT 128
#define NHID 64
#define NCLASS 16

#define NPB 196                    // dst-nodes per bucket
#define NB 511                     // ceil(N_NODES / NPB)
#define HIST_EPT 16
#define HIST_BLOCKS ((N_EDGES + 256 * HIST_EPT - 1) / (256 * HIST_EPT))  // 391
#define FILL_EPT 8
#define FILL_BLOCKS ((N_EDGES + 256 * FILL_EPT - 1) / (256 * FILL_EPT))  // 782
#define NTILES ((N_NODES + 15) / 16)            // 6250
#define GEMM_BLOCKS ((NTILES + 3) / 4)          // 1563

typedef unsigned int u32;
typedef __attribute__((ext_vector_type(8))) short bf16x8;
typedef __attribute__((ext_vector_type(4))) float f32x4;

__device__ __forceinline__ u32 pack_bf16(float a, float b) {
    u32 ua = __float_as_uint(a);
    u32 ub = __float_as_uint(b);
    ua = (ua + 0x7fffu + ((ua >> 16) & 1u)) >> 16;
    ub = (ub + 0x7fffu + ((ub >> 16) & 1u)) >> 16;
    return ua | (ub << 16);
}
__device__ __forceinline__ short f2bf(float f) {
    u32 u = __float_as_uint(f);
    u = (u + 0x7fffu + ((u >> 16) & 1u)) >> 16;
    return (short)u;
}
__device__ __forceinline__ float bf16_lo(u32 u) { return __uint_as_float(u << 16); }
__device__ __forceinline__ float bf16_hi(u32 u) { return __uint_as_float(u & 0xffff0000u); }

// per-block edge-index dtype detection: odd u32 of first 64 int64 slots are all
// zero iff data is int64 (node ids < 2^31). P(false negative) ~ (1e-5)^64 = 0.
__device__ __forceinline__ int detect_i32(const void* ei) {
    u32 v = ((const u32*)ei)[2 * (threadIdx.x & 63) + 1];
    return (__ballot(v != 0) != 0ULL) ? 1 : 0;  // 1 => int32 data
}

__device__ __forceinline__ int load_idx(const void* ei, int flag, size_t pos) {
    return flag ? ((const int*)ei)[pos] : (int)((const long long*)ei)[pos];
}

// ---------- mega1: gemm1 (MFMA) blocks first, then histA blocks ----------
// gemm1: D = W1^T (A) x x^T (B), 16 nodes per wave; lane(g=l>>4, r=l&15).
// histA: LDS-privatized coarse histogram over NB buckets (reuses Wsh as cnt).
__global__ __launch_bounds__(256) void mega1_kernel(const float* __restrict__ X,
                                                    const float* __restrict__ W,
                                                    u32* __restrict__ Y,
                                                    const void* __restrict__ ei,
                                                    int* __restrict__ ghist) {
    __shared__ float Wsh[NFEAT * NHID];  // 32 KB (hist path reuses as int cnt[512])
    int t = threadIdx.x;
    if (blockIdx.x < GEMM_BLOCKS) {
        for (int i = t; i < NFEAT * NHID; i += 256) Wsh[i] = W[i];
        __syncthreads();
        int wid = t >> 6;
        int lane = t & 63;
        int r = lane & 15, g = lane >> 4;
        int m0 = (blockIdx.x * 4 + wid) * 16;
        if (m0 >= N_NODES) return;

        bf16x8 af[4][4];  // [ntile][ktile]
#pragma unroll
        for (int nt = 0; nt < 4; ++nt)
#pragma unroll
            for (int kt = 0; kt < 4; ++kt)
#pragma unroll
                for (int j = 0; j < 8; ++j)
                    af[nt][kt][j] = f2bf(Wsh[(kt * 32 + g * 8 + j) * NHID + nt * 16 + r]);

        const float* xr = X + (size_t)(m0 + r) * NFEAT + g * 8;
        bf16x8 bfr[4];
#pragma unroll
        for (int kt = 0; kt < 4; ++kt) {
            float4 v0 = *(const float4*)(xr + kt * 32);
            float4 v1 = *(const float4*)(xr + kt * 32 + 4);
            bfr[kt][0] = f2bf(v0.x); bfr[kt][1] = f2bf(v0.y);
            bfr[kt][2] = f2bf(v0.z); bfr[kt][3] = f2bf(v0.w);
            bfr[kt][4] = f2bf(v1.x); bfr[kt][5] = f2bf(v1.y);
            bfr[kt][6] = f2bf(v1.z); bfr[kt][7] = f2bf(v1.w);
        }

        u32* yr = Y + (size_t)(m0 + r) * (NHID / 2);
#pragma unroll
        for (int nt = 0; nt < 4; ++nt) {
            f32x4 acc = {0.f, 0.f, 0.f, 0.f};
#pragma unroll
            for (int kt = 0; kt < 4; ++kt)
                acc = __builtin_amdgcn_mfma_f32_16x16x32_bf16(af[nt][kt], bfr[kt], acc, 0, 0, 0);
            uint2 o;
            o.x = pack_bf16(acc[0], acc[1]);
            o.y = pack_bf16(acc[2], acc[3]);
            *(uint2*)(yr + nt * 8 + g * 2) = o;
        }
    } else {
        int* cnt = (int*)Wsh;
        int bid = blockIdx.x - GEMM_BLOCKS;
        cnt[t] = 0;
        cnt[t + 256] = 0;
        __syncthreads();
        int f = detect_i32(ei);
        int base = bid * 256 * HIST_EPT;
#pragma unroll
        for (int k = 0; k < HIST_EPT; ++k) {
            int e = base + k * 256 + t;
            if (e < N_EDGES) {
                int d = load_idx(ei, f, (size_t)N_EDGES + e);
                atomicAdd(&cnt[d / NPB], 1);
            }
        }
        __syncthreads();
        if (cnt[t] > 0) atomicAdd(&ghist[t], cnt[t]);
        if (cnt[t + 256] > 0) atomicAdd(&ghist[t + 256], cnt[t + 256]);
    }
}

// single-block scan of NB bucket counts -> bstart (exclusive) + gcursor
__global__ __launch_bounds__(512) void scanA_kernel(const int* __restrict__ ghist,
                                                    int* __restrict__ bstart,
                                                    int* __restrict__ gcursor) {
    __shared__ int lds[512];
    int t = threadIdx.x;
    int own = (t < NB) ? ghist[t] : 0;
    lds[t] = own;
    __syncthreads();
    for (int off = 1; off < 512; off <<= 1) {
        int v = (t >= off) ? lds[t - off] : 0;
        __syncthreads();
        lds[t] += v;
        __syncthreads();
    }
    int excl = lds[t] - own;
    bstart[t] = excl;
    if (t == 511) bstart[512] = lds[511];
    if (t < NB) gcursor[t] = excl;
}

// block-privatized bin scatter: {src | dstl<<20, w} into bucket-contiguous ebuf
__global__ __launch_bounds__(256) void fillA_kernel(const void* __restrict__ ei,
                                                    const float* __restrict__ ew,
                                                    int* __restrict__ gcursor,
                                                    int2* __restrict__ ebuf) {
    __shared__ int cnt[512];
    __shared__ int base[512];
    int t = threadIdx.x;
    cnt[t] = 0;
    cnt[t + 256] = 0;
    __syncthreads();
    int f = detect_i32(ei);
    int eb = blockIdx.x * 256 * FILL_EPT;
    int src[FILL_EPT], bin[FILL_EPT], rank[FILL_EPT];
    float w[FILL_EPT];
#pragma unroll
    for (int k = 0; k < FILL_EPT; ++k) {
        int e = eb + k * 256 + t;
        bin[k] = -1;
        if (e < N_EDGES) {
            int s = load_idx(ei, f, (size_t)e);
            int d = load_idx(ei, f, (size_t)N_EDGES + e);
            int b = d / NPB;
            src[k] = s | ((d - b * NPB) << 20);
            w[k] = ew[e];
            bin[k] = b;
            rank[k] = atomicAdd(&cnt[b], 1);
        }
    }
    __syncthreads();
    if (cnt[t] > 0) base[t] = atomicAdd(&gcursor[t], cnt[t]);
    if (cnt[t + 256] > 0) base[t + 256] = atomicAdd(&gcursor[t + 256], cnt[t + 256]);
    __syncthreads();
#pragma unroll
    for (int k = 0; k < FILL_EPT; ++k) {
        if (bin[k] >= 0) {
            int pos = base[bin[k]] + rank[k];
            ebuf[pos] = make_int2(src[k], __float_as_int(w[k]));
        }
    }
}

// per-bucket counting sort -> exact CSR (ebuf2) + row_ptr
__global__ __launch_bounds__(256) void sortB_kernel(const int2* __restrict__ ebuf,
                                                    const int* __restrict__ bstart,
                                                    int2* __restrict__ ebuf2,
                                                    int* __restrict__ row_ptr) {
    __shared__ int cnt[NPB];
    __shared__ int sc[256];
    __shared__ int cur[NPB];
    int t = threadIdx.x, b = blockIdx.x;
    for (int i = t; i < NPB; i += 256) cnt[i] = 0;
    __syncthreads();
    int start = bstart[b], end = bstart[b + 1];
    for (int i = start + t; i < end; i += 256) {
        int dl = ((u32)ebuf[i].x) >> 20;
        atomicAdd(&cnt[dl], 1);
    }
    __syncthreads();
    int own = (t < NPB) ? cnt[t] : 0;
    sc[t] = own;
    __syncthreads();
    for (int off = 1; off < 256; off <<= 1) {
        int v = (t >= off) ? sc[t - off] : 0;
        __syncthreads();
        sc[t] += v;
        __syncthreads();
    }
    int excl = sc[t] - own;
    if (t < NPB) {
        cur[t] = excl;
        int node = b * NPB + t;
        if (node < N_NODES) row_ptr[node] = start + excl;
    }
    if (b == 0 && t == 0) row_ptr[N_NODES] = N_EDGES;
    __syncthreads();
    for (int i = start + t; i < end; i += 256) {
        int2 p = ebuf[i];
        int dl = ((u32)p.x) >> 20;
        int pos = start + atomicAdd(&cur[dl], 1);
        ebuf2[pos] = make_int2(p.x & 0xFFFFF, p.y);
    }
}

// ---------- agg1 + relu + gemm2 fused ----------
// One wave per node; lane = sub*8+p (8 subs); lane gathers uint4 (8 feats =
// slice 8p..8p+7); 2-deep unroll -> 16 gathers in flight per wave. Butterfly
// over sub bits (8,16,32) leaves EVERY lane with the full sum of its slice;
// relu; 16-FMA partial vs LDS-transposed W2; butterfly over p bits (1,2,4)
// yields o[2s],o[2s+1] per sub; lane p==0 writes packed class pair.
__global__ __launch_bounds__(256) void agg1f_kernel(const u32* __restrict__ xwb,
                                                    const int* __restrict__ row_ptr,
                                                    const int2* __restrict__ ep,
                                                    const float* __restrict__ W2,
                                                    u32* __restrict__ hwb) {
    __shared__ float W2t[NCLASS * NHID];  // 4 KB, transposed: W2t[c*64+k]
    int tt = threadIdx.x;
    for (int i = tt; i < NCLASS * NHID; i += 256) {
        int c = i >> 6, k = i & 63;
        W2t[i] = W2[k * NCLASS + c];
    }
    __syncthreads();
    int t = blockIdx.x * 256 + tt;
    int node = t >> 6;
    int lane = t & 63;
    int p = lane & 7;
    int sub = lane >> 3;
    if (node >= N_NODES) return;
    int start = row_ptr[node], end = row_ptr[node + 1];
    float f0 = 0.f, f1 = 0.f, f2 = 0.f, f3 = 0.f;
    float f4 = 0.f, f5 = 0.f, f6 = 0.f, f7 = 0.f;
    float g0 = 0.f, g1 = 0.f, g2 = 0.f, g3 = 0.f;
    float g4 = 0.f, g5 = 0.f, g6 = 0.f, g7 = 0.f;
    int i = start + sub;
    for (; i + 8 < end; i += 16) {
        int2 pa = ep[i];
        int2 pb = ep[i + 8];
        uint4 ua = *(const uint4*)(xwb + (size_t)pa.x * 32 + 4 * p);
        uint4 ub = *(const uint4*)(xwb + (size_t)pb.x * 32 + 4 * p);
        float wa = __int_as_float(pa.y);
        float wb = __int_as_float(pb.y);
        f0 += wa * bf16_lo(ua.x); f1 += wa * bf16_hi(ua.x);
        f2 += wa * bf16_lo(ua.y); f3 += wa * bf16_hi(ua.y);
        f4 += wa * bf16_lo(ua.z); f5 += wa * bf16_hi(ua.z);
        f6 += wa * bf16_lo(ua.w); f7 += wa * bf16_hi(ua.w);
        g0 += wb * bf16_lo(ub.x); g1 += wb * bf16_hi(ub.x);
        g2 += wb * bf16_lo(ub.y); g3 += wb * bf16_hi(ub.y);
        g4 += wb * bf16_lo(ub.z); g5 += wb * bf16_hi(ub.z);
        g6 += wb * bf16_lo(ub.w); g7 += wb * bf16_hi(ub.w);
    }
    if (i < end) {
        int2 pa = ep[i];
        uint4 ua = *(const uint4*)(xwb + (size_t)pa.x * 32 + 4 * p);
        float wa = __int_as_float(pa.y);
        f0 += wa * bf16_lo(ua.x); f1 += wa * bf16_hi(ua.x);
        f2 += wa * bf16_lo(ua.y); f3 += wa * bf16_hi(ua.y);
        f4 += wa * bf16_lo(ua.z); f5 += wa * bf16_hi(ua.z);
        f6 += wa * bf16_lo(ua.w); f7 += wa * bf16_hi(ua.w);
    }
    f0 += g0; f1 += g1; f2 += g2; f3 += g3;
    f4 += g4; f5 += g5; f6 += g6; f7 += g7;
#pragma unroll
    for (int m = 8; m <= 32; m <<= 1) {
        f0 += __shfl_xor(f0, m, 64); f1 += __shfl_xor(f1, m, 64);
        f2 += __shfl_xor(f2, m, 64); f3 += __shfl_xor(f3, m, 64);
        f4 += __shfl_xor(f4, m, 64); f5 += __shfl_xor(f5, m, 64);
        f6 += __shfl_xor(f6, m, 64); f7 += __shfl_xor(f7, m, 64);
    }
    f0 = fmaxf(f0, 0.f); f1 = fmaxf(f1, 0.f);
    f2 = fmaxf(f2, 0.f); f3 = fmaxf(f3, 0.f);
    f4 = fmaxf(f4, 0.f); f5 = fmaxf(f5, 0.f);
    f6 = fmaxf(f6, 0.f); f7 = fmaxf(f7, 0.f);
    // gemm2 partial: classes (2*sub, 2*sub+1), feats 8p..8p+7
    const float* w0 = &W2t[(2 * sub) * NHID + 8 * p];
    const float* w1 = &W2t[(2 * sub + 1) * NHID + 8 * p];
    float po0 = f0 * w0[0] + f1 * w0[1] + f2 * w0[2] + f3 * w0[3]
              + f4 * w0[4] + f5 * w0[5] + f6 * w0[6] + f7 * w0[7];
    float po1 = f0 * w1[0] + f1 * w1[1] + f2 * w1[2] + f3 * w1[3]
              + f4 * w1[4] + f5 * w1[5] + f6 * w1[6] + f7 * w1[7];
#pragma unroll
    for (int m = 1; m <= 4; m <<= 1) {
        po0 += __shfl_xor(po0, m, 64);
        po1 += __shfl_xor(po1, m, 64);
    }
    if (p == 0) hwb[(size_t)node * 8 + sub] = pack_bf16(po0, po1);
}

// Layer 2: one wave per node; lane = sub*4+p (16 subs); uint2 gathers from
// the 3.2 MB hwb (L2-resident); shfl_xor(4,8,16,32) reduce; fp32 out.
__global__ __launch_bounds__(256) void agg2_kernel(const u32* __restrict__ hwb,
                                                   const int* __restrict__ row_ptr,
                                                   const int2* __restrict__ ep,
                                                   float* __restrict__ out) {
    int t = blockIdx.x * 256 + threadIdx.x;
    int node = t >> 6;
    int lane = t & 63;
    int p = lane & 3;
    int sub = lane >> 2;
    if (node >= N_NODES) return;
    int start = row_ptr[node], end = row_ptr[node + 1];
    float f0 = 0.f, f1 = 0.f, f2 = 0.f, f3 = 0.f;
    for (int i = start + sub; i < end; i += 16) {
        int2 pr = ep[i];
        uint2 u = *(const uint2*)(hwb + (size_t)pr.x * 8 + 2 * p);
        float w = __int_as_float(pr.y);
        f0 += w * bf16_lo(u.x); f1 += w * bf16_hi(u.x);
        f2 += w * bf16_lo(u.y); f3 += w * bf16_hi(u.y);
    }
#pragma unroll
    for (int m = 4; m <= 32; m <<= 1) {
        f0 += __shfl_xor(f0, m, 64); f1 += __shfl_xor(f1, m, 64);
        f2 += __shfl_xor(f2, m, 64); f3 += __shfl_xor(f3, m, 64);
    }
    if (sub == 0) {
        *(float4*)(out + (size_t)node * NCLASS + 4 * p) = make_float4(f0, f1, f2, f3);
    }
}

extern "C" void kernel_launch(void* const* d_in, const int* in_sizes, int n_in,
                              void* d_out, int out_size, void* d_ws, size_t ws_size,
                              hipStream_t stream) {
    const float* x  = (const float*)d_in[0];
    const void*  ei = d_in[1];
    const float* ew = (const float*)d_in[2];
    const float* W1 = (const float*)d_in[3];
    const float* W2 = (const float*)d_in[4];
    float* out = (float*)d_out;

    char* ws = (char*)d_ws;
    size_t off = 0;
    auto take = [&](size_t bytes) {
        char* p = ws + off;
        off += (bytes + 511) & ~(size_t)511;
        return p;
    };
    int*   ghist   = (int*)take(512 * 4);
    int*   bstart  = (int*)take(513 * 4);
    int*   gcursor = (int*)take(512 * 4);
    int*   row_ptr = (int*)take((size_t)(N_NODES + 1) * 4);
    int2*  ebuf    = (int2*)take((size_t)N_EDGES * 8);
    int2*  ebuf2   = (int2*)take((size_t)N_EDGES * 8);
    u32*   xwb     = (u32*)take((size_t)N_NODES * (NHID / 2) * 4);   // bf16 packed
    u32*   hwb     = (u32*)take((size_t)N_NODES * (NCLASS / 2) * 4); // bf16 packed

    hipMemsetAsync(ghist, 0, 512 * 4, stream);
    mega1_kernel<<<GEMM_BLOCKS + HIST_BLOCKS, 256, 0, stream>>>(x, W1, xwb, ei, ghist);
    scanA_kernel<<<1, 512, 0, stream>>>(ghist, bstart, gcursor);
    fillA_kernel<<<FILL_BLOCKS, 256, 0, stream>>>(ei, ew, gcursor, ebuf);
    sortB_kernel<<<NB, 256, 0, stream>>>(ebuf, bstart, ebuf2, row_ptr);

    agg1f_kernel<<<(N_NODES * 64 + 255) / 256, 256, 0, stream>>>(xwb, row_ptr, ebuf2, W2, hwb);
    agg2_kernel<<<(N_NODES * 64 + 255) / 256, 256, 0, stream>>>(hwb, row_ptr, ebuf2, out);
}

// Round 10
// 159.735 us; speedup vs baseline: 1.2063x; 1.2063x over previous
//
#include <hip/hip_runtime.h>
#include <hip/hip_fp16.h>

#define N_NODES 100000
#define N_EDGES 1600000
#define NFEAT 128
#define NHID 64
#define NCLASS 16

#define NPB 196                    // dst-nodes per bucket
#define NB 511                     // ceil(N_NODES / NPB)
#define HIST_EPT 16
#define HIST_BLOCKS ((N_EDGES + 256 * HIST_EPT - 1) / (256 * HIST_EPT))  // 391
#define FILL_EPT 8
#define FILL_BLOCKS ((N_EDGES + 256 * FILL_EPT - 1) / (256 * FILL_EPT))  // 782
#define NTILES ((N_NODES + 15) / 16)            // 6250
#define GEMM_BLOCKS ((NTILES + 3) / 4)          // 1563

typedef unsigned int u32;
typedef __attribute__((ext_vector_type(8))) _Float16 f16x8;
typedef __attribute__((ext_vector_type(4))) float f32x4;

__device__ __forceinline__ __half2 u2h2(u32 u) { __half2 h; __builtin_memcpy(&h, &u, 4); return h; }
__device__ __forceinline__ u32 h22u(__half2 h) { u32 u; __builtin_memcpy(&u, &h, 4); return u; }
__device__ __forceinline__ u32 pack_h16(float a, float b) { return h22u(__floats2half2_rn(a, b)); }

// per-block edge-index dtype detection: odd u32 of first 64 int64 slots are all
// zero iff data is int64 (node ids < 2^31).
__device__ __forceinline__ int detect_i32(const void* ei) {
    u32 v = ((const u32*)ei)[2 * (threadIdx.x & 63) + 1];
    return (__ballot(v != 0) != 0ULL) ? 1 : 0;  // 1 => int32 data
}

__device__ __forceinline__ int load_idx(const void* ei, int flag, size_t pos) {
    return flag ? ((const int*)ei)[pos] : (int)((const long long*)ei)[pos];
}

// ---------- mega1: gemm1 (MFMA f16) blocks first, then histA blocks ----------
// gemm1: D = W1^T (A) x x^T (B), 16 nodes per wave; lane(g=l>>4, r=l&15).
__global__ __launch_bounds__(256) void mega1_kernel(const float* __restrict__ X,
                                                    const float* __restrict__ W,
                                                    u32* __restrict__ Y,
                                                    const void* __restrict__ ei,
                                                    int* __restrict__ ghist) {
    __shared__ float Wsh[NFEAT * NHID];  // 32 KB (hist path reuses as int cnt[512])
    int t = threadIdx.x;
    if (blockIdx.x < GEMM_BLOCKS) {
        for (int i = t; i < NFEAT * NHID; i += 256) Wsh[i] = W[i];
        __syncthreads();
        int wid = t >> 6;
        int lane = t & 63;
        int r = lane & 15, g = lane >> 4;
        int m0 = (blockIdx.x * 4 + wid) * 16;
        if (m0 >= N_NODES) return;

        f16x8 af[4][4];  // [ntile][ktile]
#pragma unroll
        for (int nt = 0; nt < 4; ++nt)
#pragma unroll
            for (int kt = 0; kt < 4; ++kt)
#pragma unroll
                for (int j = 0; j < 8; ++j)
                    af[nt][kt][j] = (_Float16)Wsh[(kt * 32 + g * 8 + j) * NHID + nt * 16 + r];

        const float* xr = X + (size_t)(m0 + r) * NFEAT + g * 8;
        f16x8 bfr[4];
#pragma unroll
        for (int kt = 0; kt < 4; ++kt) {
            float4 v0 = *(const float4*)(xr + kt * 32);
            float4 v1 = *(const float4*)(xr + kt * 32 + 4);
            bfr[kt][0] = (_Float16)v0.x; bfr[kt][1] = (_Float16)v0.y;
            bfr[kt][2] = (_Float16)v0.z; bfr[kt][3] = (_Float16)v0.w;
            bfr[kt][4] = (_Float16)v1.x; bfr[kt][5] = (_Float16)v1.y;
            bfr[kt][6] = (_Float16)v1.z; bfr[kt][7] = (_Float16)v1.w;
        }

        u32* yr = Y + (size_t)(m0 + r) * (NHID / 2);
#pragma unroll
        for (int nt = 0; nt < 4; ++nt) {
            f32x4 acc = {0.f, 0.f, 0.f, 0.f};
#pragma unroll
            for (int kt = 0; kt < 4; ++kt)
                acc = __builtin_amdgcn_mfma_f32_16x16x32_f16(af[nt][kt], bfr[kt], acc, 0, 0, 0);
            uint2 o;
            o.x = pack_h16(acc[0], acc[1]);
            o.y = pack_h16(acc[2], acc[3]);
            *(uint2*)(yr + nt * 8 + g * 2) = o;
        }
    } else {
        int* cnt = (int*)Wsh;
        int bid = blockIdx.x - GEMM_BLOCKS;
        cnt[t] = 0;
        cnt[t + 256] = 0;
        __syncthreads();
        int f = detect_i32(ei);
        int base = bid * 256 * HIST_EPT;
#pragma unroll
        for (int k = 0; k < HIST_EPT; ++k) {
            int e = base + k * 256 + t;
            if (e < N_EDGES) {
                int d = load_idx(ei, f, (size_t)N_EDGES + e);
                atomicAdd(&cnt[d / NPB], 1);
            }
        }
        __syncthreads();
        if (cnt[t] > 0) atomicAdd(&ghist[t], cnt[t]);
        if (cnt[t + 256] > 0) atomicAdd(&ghist[t + 256], cnt[t + 256]);
    }
}

// single-block scan of NB bucket counts -> bstart (exclusive) + gcursor
__global__ __launch_bounds__(512) void scanA_kernel(const int* __restrict__ ghist,
                                                    int* __restrict__ bstart,
                                                    int* __restrict__ gcursor) {
    __shared__ int lds[512];
    int t = threadIdx.x;
    int own = (t < NB) ? ghist[t] : 0;
    lds[t] = own;
    __syncthreads();
    for (int off = 1; off < 512; off <<= 1) {
        int v = (t >= off) ? lds[t - off] : 0;
        __syncthreads();
        lds[t] += v;
        __syncthreads();
    }
    int excl = lds[t] - own;
    bstart[t] = excl;
    if (t == 511) bstart[512] = lds[511];
    if (t < NB) gcursor[t] = excl;
}

// block-privatized bin scatter: {src | dstl<<20, w} into bucket-contiguous ebuf
__global__ __launch_bounds__(256) void fillA_kernel(const void* __restrict__ ei,
                                                    const float* __restrict__ ew,
                                                    int* __restrict__ gcursor,
                                                    int2* __restrict__ ebuf) {
    __shared__ int cnt[512];
    __shared__ int base[512];
    int t = threadIdx.x;
    cnt[t] = 0;
    cnt[t + 256] = 0;
    __syncthreads();
    int f = detect_i32(ei);
    int eb = blockIdx.x * 256 * FILL_EPT;
    int src[FILL_EPT], bin[FILL_EPT], rank[FILL_EPT];
    float w[FILL_EPT];
#pragma unroll
    for (int k = 0; k < FILL_EPT; ++k) {
        int e = eb + k * 256 + t;
        bin[k] = -1;
        if (e < N_EDGES) {
            int s = load_idx(ei, f, (size_t)e);
            int d = load_idx(ei, f, (size_t)N_EDGES + e);
            int b = d / NPB;
            src[k] = s | ((d - b * NPB) << 20);
            w[k] = ew[e];
            bin[k] = b;
            rank[k] = atomicAdd(&cnt[b], 1);
        }
    }
    __syncthreads();
    if (cnt[t] > 0) base[t] = atomicAdd(&gcursor[t], cnt[t]);
    if (cnt[t + 256] > 0) base[t + 256] = atomicAdd(&gcursor[t + 256], cnt[t + 256]);
    __syncthreads();
#pragma unroll
    for (int k = 0; k < FILL_EPT; ++k) {
        if (bin[k] >= 0) {
            int pos = base[bin[k]] + rank[k];
            ebuf[pos] = make_int2(src[k], __float_as_int(w[k]));
        }
    }
}

// per-bucket counting sort -> exact CSR (ebuf2) + row_ptr
__global__ __launch_bounds__(256) void sortB_kernel(const int2* __restrict__ ebuf,
                                                    const int* __restrict__ bstart,
                                                    int2* __restrict__ ebuf2,
                                                    int* __restrict__ row_ptr) {
    __shared__ int cnt[NPB];
    __shared__ int sc[256];
    __shared__ int cur[NPB];
    int t = threadIdx.x, b = blockIdx.x;
    for (int i = t; i < NPB; i += 256) cnt[i] = 0;
    __syncthreads();
    int start = bstart[b], end = bstart[b + 1];
    for (int i = start + t; i < end; i += 256) {
        int dl = ((u32)ebuf[i].x) >> 20;
        atomicAdd(&cnt[dl], 1);
    }
    __syncthreads();
    int own = (t < NPB) ? cnt[t] : 0;
    sc[t] = own;
    __syncthreads();
    for (int off = 1; off < 256; off <<= 1) {
        int v = (t >= off) ? sc[t - off] : 0;
        __syncthreads();
        sc[t] += v;
        __syncthreads();
    }
    int excl = sc[t] - own;
    if (t < NPB) {
        cur[t] = excl;
        int node = b * NPB + t;
        if (node < N_NODES) row_ptr[node] = start + excl;
    }
    if (b == 0 && t == 0) row_ptr[N_NODES] = N_EDGES;
    __syncthreads();
    for (int i = start + t; i < end; i += 256) {
        int2 p = ebuf[i];
        int dl = ((u32)p.x) >> 20;
        int pos = start + atomicAdd(&cur[dl], 1);
        ebuf2[pos] = make_int2(p.x & 0xFFFFF, p.y);
    }
}

// ---------- gemm2 via MFMA f16: D = W2^T x h^T; B-frags load packed-f16 h ----------
__global__ __launch_bounds__(256) void gemm2_kernel(const u32* __restrict__ Hb,
                                                    const float* __restrict__ W,
                                                    u32* __restrict__ Y) {
    __shared__ float Wsh[NHID * NCLASS];  // 4 KB
    int t = threadIdx.x;
    for (int i = t; i < NHID * NCLASS; i += 256) Wsh[i] = W[i];
    __syncthreads();
    int wid = t >> 6;
    int lane = t & 63;
    int r = lane & 15, g = lane >> 4;
    int m0 = (blockIdx.x * 4 + wid) * 16;
    if (m0 >= N_NODES) return;

    f16x8 af[2];
#pragma unroll
    for (int kt = 0; kt < 2; ++kt)
#pragma unroll
        for (int j = 0; j < 8; ++j)
            af[kt][j] = (_Float16)Wsh[(kt * 32 + g * 8 + j) * NCLASS + r];

    const u32* hr = Hb + (size_t)(m0 + r) * (NHID / 2) + g * 4;
    union { uint4 u; f16x8 h; } b0, b1;
    b0.u = *(const uint4*)(hr + 0);
    b1.u = *(const uint4*)(hr + 16);

    f32x4 acc = {0.f, 0.f, 0.f, 0.f};
    acc = __builtin_amdgcn_mfma_f32_16x16x32_f16(af[0], b0.h, acc, 0, 0, 0);
    acc = __builtin_amdgcn_mfma_f32_16x16x32_f16(af[1], b1.h, acc, 0, 0, 0);

    u32* yr = Y + (size_t)(m0 + r) * (NCLASS / 2);
    uint2 o;
    o.x = pack_h16(acc[0], acc[1]);
    o.y = pack_h16(acc[2], acc[3]);
    *(uint2*)(yr + g * 2) = o;
}

// ---------- CSR aggregation with packed-f16 math (v_pk_fma_f16) ----------
// Layer 1: one wave per node; lane = sub*16+p (4 subs); lane gathers uint2
// (4 feats as 2 half2); 2-deep unroll -> 8 gathers in flight; __hfma2
// accumulate; half2 butterfly over sub bits; relu + store at sub==0.
__global__ __launch_bounds__(256) void agg1_kernel(const u32* __restrict__ xwb,
                                                   const int* __restrict__ row_ptr,
                                                   const int2* __restrict__ ep,
                                                   u32* __restrict__ hb) {
    int t = blockIdx.x * 256 + threadIdx.x;
    int node = t >> 6;
    int lane = t & 63;
    int p = lane & 15;
    int sub = lane >> 4;
    if (node >= N_NODES) return;
    int start = row_ptr[node], end = row_ptr[node + 1];
    __half2 a0 = u2h2(0), a1 = u2h2(0), b0 = u2h2(0), b1 = u2h2(0);
    int i = start + sub;
    for (; i + 4 < end; i += 8) {
        int2 pa = ep[i];
        int2 pb = ep[i + 4];
        uint2 ua = *(const uint2*)(xwb + (size_t)pa.x * 32 + 2 * p);
        uint2 ub = *(const uint2*)(xwb + (size_t)pb.x * 32 + 2 * p);
        __half2 wa = __half2half2(__float2half(__int_as_float(pa.y)));
        __half2 wb = __half2half2(__float2half(__int_as_float(pb.y)));
        a0 = __hfma2(u2h2(ua.x), wa, a0);
        a1 = __hfma2(u2h2(ua.y), wa, a1);
        b0 = __hfma2(u2h2(ub.x), wb, b0);
        b1 = __hfma2(u2h2(ub.y), wb, b1);
    }
    if (i < end) {
        int2 pa = ep[i];
        uint2 ua = *(const uint2*)(xwb + (size_t)pa.x * 32 + 2 * p);
        __half2 wa = __half2half2(__float2half(__int_as_float(pa.y)));
        a0 = __hfma2(u2h2(ua.x), wa, a0);
        a1 = __hfma2(u2h2(ua.y), wa, a1);
    }
    a0 = __hadd2(a0, b0);
    a1 = __hadd2(a1, b1);
#pragma unroll
    for (int m = 16; m <= 32; m <<= 1) {
        a0 = __hadd2(a0, u2h2((u32)__shfl_xor((int)h22u(a0), m, 64)));
        a1 = __hadd2(a1, u2h2((u32)__shfl_xor((int)h22u(a1), m, 64)));
    }
    if (sub == 0) {
        float2 f0 = __half22float2(a0);
        float2 f1 = __half22float2(a1);
        uint2 o;
        o.x = pack_h16(fmaxf(f0.x, 0.f), fmaxf(f0.y, 0.f));
        o.y = pack_h16(fmaxf(f1.x, 0.f), fmaxf(f1.y, 0.f));
        *(uint2*)(hb + (size_t)node * 32 + 2 * p) = o;
    }
}

// Layer 2: one wave per node; lane = sub*4+p (16 subs); uint2 gathers from
// the 3.2 MB hwb (L2-resident); __hfma2 accumulate; butterfly 4..32; fp32 out.
__global__ __launch_bounds__(256) void agg2_kernel(const u32* __restrict__ hwb,
                                                   const int* __restrict__ row_ptr,
                                                   const int2* __restrict__ ep,
                                                   float* __restrict__ out) {
    int t = blockIdx.x * 256 + threadIdx.x;
    int node = t >> 6;
    int lane = t & 63;
    int p = lane & 3;
    int sub = lane >> 2;
    if (node >= N_NODES) return;
    int start = row_ptr[node], end = row_ptr[node + 1];
    __half2 a0 = u2h2(0), a1 = u2h2(0);
    for (int i = start + sub; i < end; i += 16) {
        int2 pr = ep[i];
        uint2 u = *(const uint2*)(hwb + (size_t)pr.x * 8 + 2 * p);
        __half2 w2 = __half2half2(__float2half(__int_as_float(pr.y)));
        a0 = __hfma2(u2h2(u.x), w2, a0);
        a1 = __hfma2(u2h2(u.y), w2, a1);
    }
#pragma unroll
    for (int m = 4; m <= 32; m <<= 1) {
        a0 = __hadd2(a0, u2h2((u32)__shfl_xor((int)h22u(a0), m, 64)));
        a1 = __hadd2(a1, u2h2((u32)__shfl_xor((int)h22u(a1), m, 64)));
    }
    if (sub == 0) {
        float2 f0 = __half22float2(a0);
        float2 f1 = __half22float2(a1);
        *(float4*)(out + (size_t)node * NCLASS + 4 * p) =
            make_float4(f0.x, f0.y, f1.x, f1.y);
    }
}

extern "C" void kernel_launch(void* const* d_in, const int* in_sizes, int n_in,
                              void* d_out, int out_size, void* d_ws, size_t ws_size,
                              hipStream_t stream) {
    const float* x  = (const float*)d_in[0];
    const void*  ei = d_in[1];
    const float* ew = (const float*)d_in[2];
    const float* W1 = (const float*)d_in[3];
    const float* W2 = (const float*)d_in[4];
    float* out = (float*)d_out;

    char* ws = (char*)d_ws;
    size_t off = 0;
    auto take = [&](size_t bytes) {
        char* p = ws + off;
        off += (bytes + 511) & ~(size_t)511;
        return p;
    };
    int*   ghist   = (int*)take(512 * 4);
    int*   bstart  = (int*)take(513 * 4);
    int*   gcursor = (int*)take(512 * 4);
    int*   row_ptr = (int*)take((size_t)(N_NODES + 1) * 4);
    int2*  ebuf    = (int2*)take((size_t)N_EDGES * 8);
    int2*  ebuf2   = (int2*)take((size_t)N_EDGES * 8);
    u32*   xwb     = (u32*)take((size_t)N_NODES * (NHID / 2) * 4);   // f16 packed
    u32*   hb      = (u32*)take((size_t)N_NODES * (NHID / 2) * 4);   // f16 packed
    u32*   hwb     = (u32*)take((size_t)N_NODES * (NCLASS / 2) * 4); // f16 packed

    hipMemsetAsync(ghist, 0, 512 * 4, stream);
    mega1_kernel<<<GEMM_BLOCKS + HIST_BLOCKS, 256, 0, stream>>>(x, W1, xwb, ei, ghist);
    scanA_kernel<<<1, 512, 0, stream>>>(ghist, bstart, gcursor);
    fillA_kernel<<<FILL_BLOCKS, 256, 0, stream>>>(ei, ew, gcursor, ebuf);
    sortB_kernel<<<NB, 256, 0, stream>>>(ebuf, bstart, ebuf2, row_ptr);

    agg1_kernel<<<(N_NODES * 64 + 255) / 256, 256, 0, stream>>>(xwb, row_ptr, ebuf2, hb);
    gemm2_kernel<<<GEMM_BLOCKS, 256, 0, stream>>>(hb, W2, hwb);
    agg2_kernel<<<(N_NODES * 64 + 255) / 256, 256, 0, stream>>>(hwb, row_ptr, ebuf2, out);
}

// Round 11
// 156.809 us; speedup vs baseline: 1.2288x; 1.0187x over previous
//
#include <hip/hip_runtime.h>
#include <hip/hip_fp16.h>

#define N_NODES 100000
#define N_EDGES 1600000
#define NFEAT 128
#define NHID 64
#define NCLASS 16

#define NPB 98                     // dst-nodes per bucket
#define NB 1024                    // ceil(100000 / 98) = 1021 -> pad to 1024
#define HIST_EPT 16
#define HIST_BLOCKS ((N_EDGES + 256 * HIST_EPT - 1) / (256 * HIST_EPT))  // 391
#define FILL_EPT 8
#define FILL_BLOCKS ((N_EDGES + 256 * FILL_EPT - 1) / (256 * FILL_EPT))  // 782
#define NTILES ((N_NODES + 15) / 16)            // 6250
#define GEMM_BLOCKS ((NTILES + 3) / 4)          // 1563

typedef unsigned int u32;
typedef __attribute__((ext_vector_type(8))) _Float16 f16x8;
typedef __attribute__((ext_vector_type(4))) float f32x4;

__device__ __forceinline__ __half2 u2h2(u32 u) { __half2 h; __builtin_memcpy(&h, &u, 4); return h; }
__device__ __forceinline__ u32 h22u(__half2 h) { u32 u; __builtin_memcpy(&u, &h, 4); return u; }
__device__ __forceinline__ u32 pack_h16(float a, float b) { return h22u(__floats2half2_rn(a, b)); }

// per-block edge-index dtype detection: odd u32 of first 64 int64 slots are all
// zero iff data is int64 (node ids < 2^31).
__device__ __forceinline__ int detect_i32(const void* ei) {
    u32 v = ((const u32*)ei)[2 * (threadIdx.x & 63) + 1];
    return (__ballot(v != 0) != 0ULL) ? 1 : 0;  // 1 => int32 data
}

__device__ __forceinline__ int load_idx(const void* ei, int flag, size_t pos) {
    return flag ? ((const int*)ei)[pos] : (int)((const long long*)ei)[pos];
}

// ---------- mega1: gemm1 (MFMA f16) blocks first, then histA blocks ----------
__global__ __launch_bounds__(256) void mega1_kernel(const float* __restrict__ X,
                                                    const float* __restrict__ W,
                                                    u32* __restrict__ Y,
                                                    const void* __restrict__ ei,
                                                    int* __restrict__ ghist) {
    __shared__ float Wsh[NFEAT * NHID];  // 32 KB (hist path reuses as int cnt[NB])
    int t = threadIdx.x;
    if (blockIdx.x < GEMM_BLOCKS) {
        for (int i = t; i < NFEAT * NHID; i += 256) Wsh[i] = W[i];
        __syncthreads();
        int wid = t >> 6;
        int lane = t & 63;
        int r = lane & 15, g = lane >> 4;
        int m0 = (blockIdx.x * 4 + wid) * 16;
        if (m0 >= N_NODES) return;

        f16x8 af[4][4];  // [ntile][ktile]
#pragma unroll
        for (int nt = 0; nt < 4; ++nt)
#pragma unroll
            for (int kt = 0; kt < 4; ++kt)
#pragma unroll
                for (int j = 0; j < 8; ++j)
                    af[nt][kt][j] = (_Float16)Wsh[(kt * 32 + g * 8 + j) * NHID + nt * 16 + r];

        const float* xr = X + (size_t)(m0 + r) * NFEAT + g * 8;
        f16x8 bfr[4];
#pragma unroll
        for (int kt = 0; kt < 4; ++kt) {
            float4 v0 = *(const float4*)(xr + kt * 32);
            float4 v1 = *(const float4*)(xr + kt * 32 + 4);
            bfr[kt][0] = (_Float16)v0.x; bfr[kt][1] = (_Float16)v0.y;
            bfr[kt][2] = (_Float16)v0.z; bfr[kt][3] = (_Float16)v0.w;
            bfr[kt][4] = (_Float16)v1.x; bfr[kt][5] = (_Float16)v1.y;
            bfr[kt][6] = (_Float16)v1.z; bfr[kt][7] = (_Float16)v1.w;
        }

        u32* yr = Y + (size_t)(m0 + r) * (NHID / 2);
#pragma unroll
        for (int nt = 0; nt < 4; ++nt) {
            f32x4 acc = {0.f, 0.f, 0.f, 0.f};
#pragma unroll
            for (int kt = 0; kt < 4; ++kt)
                acc = __builtin_amdgcn_mfma_f32_16x16x32_f16(af[nt][kt], bfr[kt], acc, 0, 0, 0);
            uint2 o;
            o.x = pack_h16(acc[0], acc[1]);
            o.y = pack_h16(acc[2], acc[3]);
            *(uint2*)(yr + nt * 8 + g * 2) = o;
        }
    } else {
        int* cnt = (int*)Wsh;
        int bid = blockIdx.x - GEMM_BLOCKS;
#pragma unroll
        for (int k = 0; k < NB / 256; ++k) cnt[t + k * 256] = 0;
        __syncthreads();
        int f = detect_i32(ei);
        int base = bid * 256 * HIST_EPT;
#pragma unroll
        for (int k = 0; k < HIST_EPT; ++k) {
            int e = base + k * 256 + t;
            if (e < N_EDGES) {
                int d = load_idx(ei, f, (size_t)N_EDGES + e);
                atomicAdd(&cnt[d / NPB], 1);
            }
        }
        __syncthreads();
#pragma unroll
        for (int k = 0; k < NB / 256; ++k)
            if (cnt[t + k * 256] > 0) atomicAdd(&ghist[t + k * 256], cnt[t + k * 256]);
    }
}

// single-block scan of NB bucket counts -> bstart (exclusive) + gcursor
__global__ __launch_bounds__(1024) void scanA_kernel(const int* __restrict__ ghist,
                                                     int* __restrict__ bstart,
                                                     int* __restrict__ gcursor) {
    __shared__ int lds[NB];
    int t = threadIdx.x;
    int own = ghist[t];
    lds[t] = own;
    __syncthreads();
    for (int off = 1; off < NB; off <<= 1) {
        int v = (t >= off) ? lds[t - off] : 0;
        __syncthreads();
        lds[t] += v;
        __syncthreads();
    }
    int excl = lds[t] - own;
    bstart[t] = excl;
    if (t == NB - 1) bstart[NB] = lds[NB - 1];
    gcursor[t] = excl;
}

// block-privatized bin scatter: {src | dstl<<20, w} into bucket-contiguous ebuf
__global__ __launch_bounds__(256) void fillA_kernel(const void* __restrict__ ei,
                                                    const float* __restrict__ ew,
                                                    int* __restrict__ gcursor,
                                                    int2* __restrict__ ebuf) {
    __shared__ int cnt[NB];
    __shared__ int base[NB];
    int t = threadIdx.x;
#pragma unroll
    for (int k = 0; k < NB / 256; ++k) cnt[t + k * 256] = 0;
    __syncthreads();
    int f = detect_i32(ei);
    int eb = blockIdx.x * 256 * FILL_EPT;
    int src[FILL_EPT], bin[FILL_EPT], rank[FILL_EPT];
    float w[FILL_EPT];
#pragma unroll
    for (int k = 0; k < FILL_EPT; ++k) {
        int e = eb + k * 256 + t;
        bin[k] = -1;
        if (e < N_EDGES) {
            int s = load_idx(ei, f, (size_t)e);
            int d = load_idx(ei, f, (size_t)N_EDGES + e);
            int b = d / NPB;
            src[k] = s | ((d - b * NPB) << 20);
            w[k] = ew[e];
            bin[k] = b;
            rank[k] = atomicAdd(&cnt[b], 1);
        }
    }
    __syncthreads();
#pragma unroll
    for (int k = 0; k < NB / 256; ++k)
        if (cnt[t + k * 256] > 0) base[t + k * 256] = atomicAdd(&gcursor[t + k * 256], cnt[t + k * 256]);
    __syncthreads();
#pragma unroll
    for (int k = 0; k < FILL_EPT; ++k) {
        if (bin[k] >= 0) {
            int pos = base[bin[k]] + rank[k];
            ebuf[pos] = make_int2(src[k], __float_as_int(w[k]));
        }
    }
}

// per-bucket counting sort -> exact CSR (ebuf2) + row_ptr
__global__ __launch_bounds__(256) void sortB_kernel(const int2* __restrict__ ebuf,
                                                    const int* __restrict__ bstart,
                                                    int2* __restrict__ ebuf2,
                                                    int* __restrict__ row_ptr) {
    __shared__ int cnt[NPB];
    __shared__ int sc[256];
    __shared__ int cur[NPB];
    int t = threadIdx.x, b = blockIdx.x;
    if (t < NPB) cnt[t] = 0;
    __syncthreads();
    int start = bstart[b], end = bstart[b + 1];
    for (int i = start + t; i < end; i += 256) {
        int dl = ((u32)ebuf[i].x) >> 20;
        atomicAdd(&cnt[dl], 1);
    }
    __syncthreads();
    int own = (t < NPB) ? cnt[t] : 0;
    sc[t] = own;
    __syncthreads();
    for (int off = 1; off < 256; off <<= 1) {
        int v = (t >= off) ? sc[t - off] : 0;
        __syncthreads();
        sc[t] += v;
        __syncthreads();
    }
    int excl = sc[t] - own;
    if (t < NPB) {
        cur[t] = excl;
        int node = b * NPB + t;
        if (node < N_NODES) row_ptr[node] = start + excl;
    }
    if (b == 0 && t == 0) row_ptr[N_NODES] = N_EDGES;
    __syncthreads();
    for (int i = start + t; i < end; i += 256) {
        int2 p = ebuf[i];
        int dl = ((u32)p.x) >> 20;
        int pos = start + atomicAdd(&cur[dl], 1);
        ebuf2[pos] = make_int2(p.x & 0xFFFFF, p.y);
    }
}

// ---------- gemm2 via MFMA f16: D = W2^T x h^T; B-frags load packed-f16 h ----------
__global__ __launch_bounds__(256) void gemm2_kernel(const u32* __restrict__ Hb,
                                                    const float* __restrict__ W,
                                                    u32* __restrict__ Y) {
    __shared__ float Wsh[NHID * NCLASS];  // 4 KB
    int t = threadIdx.x;
    for (int i = t; i < NHID * NCLASS; i += 256) Wsh[i] = W[i];
    __syncthreads();
    int wid = t >> 6;
    int lane = t & 63;
    int r = lane & 15, g = lane >> 4;
    int m0 = (blockIdx.x * 4 + wid) * 16;
    if (m0 >= N_NODES) return;

    f16x8 af[2];
#pragma unroll
    for (int kt = 0; kt < 2; ++kt)
#pragma unroll
        for (int j = 0; j < 8; ++j)
            af[kt][j] = (_Float16)Wsh[(kt * 32 + g * 8 + j) * NCLASS + r];

    const u32* hr = Hb + (size_t)(m0 + r) * (NHID / 2) + g * 4;
    union { uint4 u; f16x8 h; } b0, b1;
    b0.u = *(const uint4*)(hr + 0);
    b1.u = *(const uint4*)(hr + 16);

    f32x4 acc = {0.f, 0.f, 0.f, 0.f};
    acc = __builtin_amdgcn_mfma_f32_16x16x32_f16(af[0], b0.h, acc, 0, 0, 0);
    acc = __builtin_amdgcn_mfma_f32_16x16x32_f16(af[1], b1.h, acc, 0, 0, 0);

    u32* yr = Y + (size_t)(m0 + r) * (NCLASS / 2);
    uint2 o;
    o.x = pack_h16(acc[0], acc[1]);
    o.y = pack_h16(acc[2], acc[3]);
    *(uint2*)(yr + g * 2) = o;
}

// ---------- CSR aggregation with packed-f16 math ----------
// Layer 1: one wave per node; lane = sub*16+p (4 subs); 4-deep masked unroll
// -> 16 uint2 gathers in flight per wave; __hfma2 accumulate; butterfly 16,32.
__global__ __launch_bounds__(256) void agg1_kernel(const u32* __restrict__ xwb,
                                                   const int* __restrict__ row_ptr,
                                                   const int2* __restrict__ ep,
                                                   u32* __restrict__ hb) {
    int t = blockIdx.x * 256 + threadIdx.x;
    int node = t >> 6;
    int lane = t & 63;
    int p = lane & 15;
    int sub = lane >> 4;
    if (node >= N_NODES) return;
    int start = row_ptr[node], end = row_ptr[node + 1];
    int last = end - 1;
    __half2 a0 = u2h2(0), a1 = u2h2(0), b0 = u2h2(0), b1 = u2h2(0);
    for (int i = start + sub; i < end; i += 16) {
        int j1 = min(i + 4, last), j2 = min(i + 8, last), j3 = min(i + 12, last);
        int2 p0 = ep[i];
        int2 p1 = ep[j1];
        int2 p2 = ep[j2];
        int2 p3 = ep[j3];
        uint2 u0 = *(const uint2*)(xwb + (size_t)p0.x * 32 + 2 * p);
        uint2 u1 = *(const uint2*)(xwb + (size_t)p1.x * 32 + 2 * p);
        uint2 u2 = *(const uint2*)(xwb + (size_t)p2.x * 32 + 2 * p);
        uint2 u3 = *(const uint2*)(xwb + (size_t)p3.x * 32 + 2 * p);
        float w0f = __int_as_float(p0.y);
        float w1f = (i + 4 < end) ? __int_as_float(p1.y) : 0.f;
        float w2f = (i + 8 < end) ? __int_as_float(p2.y) : 0.f;
        float w3f = (i + 12 < end) ? __int_as_float(p3.y) : 0.f;
        __half2 w0 = __half2half2(__float2half(w0f));
        __half2 w1 = __half2half2(__float2half(w1f));
        __half2 w2 = __half2half2(__float2half(w2f));
        __half2 w3 = __half2half2(__float2half(w3f));
        a0 = __hfma2(u2h2(u0.x), w0, a0); a1 = __hfma2(u2h2(u0.y), w0, a1);
        b0 = __hfma2(u2h2(u1.x), w1, b0); b1 = __hfma2(u2h2(u1.y), w1, b1);
        a0 = __hfma2(u2h2(u2.x), w2, a0); a1 = __hfma2(u2h2(u2.y), w2, a1);
        b0 = __hfma2(u2h2(u3.x), w3, b0); b1 = __hfma2(u2h2(u3.y), w3, b1);
    }
    a0 = __hadd2(a0, b0);
    a1 = __hadd2(a1, b1);
#pragma unroll
    for (int m = 16; m <= 32; m <<= 1) {
        a0 = __hadd2(a0, u2h2((u32)__shfl_xor((int)h22u(a0), m, 64)));
        a1 = __hadd2(a1, u2h2((u32)__shfl_xor((int)h22u(a1), m, 64)));
    }
    if (sub == 0) {
        float2 f0 = __half22float2(a0);
        float2 f1 = __half22float2(a1);
        uint2 o;
        o.x = pack_h16(fmaxf(f0.x, 0.f), fmaxf(f0.y, 0.f));
        o.y = pack_h16(fmaxf(f1.x, 0.f), fmaxf(f1.y, 0.f));
        *(uint2*)(hb + (size_t)node * 32 + 2 * p) = o;
    }
}

// Layer 2: one wave per node; lane = sub*4+p (16 subs); 2-deep masked unroll
// -> 32 edges in flight; gathers hit the 3.2 MB L2-resident hwb.
__global__ __launch_bounds__(256) void agg2_kernel(const u32* __restrict__ hwb,
                                                   const int* __restrict__ row_ptr,
                                                   const int2* __restrict__ ep,
                                                   float* __restrict__ out) {
    int t = blockIdx.x * 256 + threadIdx.x;
    int node = t >> 6;
    int lane = t & 63;
    int p = lane & 3;
    int sub = lane >> 2;
    if (node >= N_NODES) return;
    int start = row_ptr[node], end = row_ptr[node + 1];
    int last = end - 1;
    __half2 a0 = u2h2(0), a1 = u2h2(0), b0 = u2h2(0), b1 = u2h2(0);
    for (int i = start + sub; i < end; i += 32) {
        int j1 = min(i + 16, last);
        int2 p0 = ep[i];
        int2 p1 = ep[j1];
        uint2 u0 = *(const uint2*)(hwb + (size_t)p0.x * 8 + 2 * p);
        uint2 u1 = *(const uint2*)(hwb + (size_t)p1.x * 8 + 2 * p);
        float w0f = __int_as_float(p0.y);
        float w1f = (i + 16 < end) ? __int_as_float(p1.y) : 0.f;
        __half2 w0 = __half2half2(__float2half(w0f));
        __half2 w1 = __half2half2(__float2half(w1f));
        a0 = __hfma2(u2h2(u0.x), w0, a0); a1 = __hfma2(u2h2(u0.y), w0, a1);
        b0 = __hfma2(u2h2(u1.x), w1, b0); b1 = __hfma2(u2h2(u1.y), w1, b1);
    }
    a0 = __hadd2(a0, b0);
    a1 = __hadd2(a1, b1);
#pragma unroll
    for (int m = 4; m <= 32; m <<= 1) {
        a0 = __hadd2(a0, u2h2((u32)__shfl_xor((int)h22u(a0), m, 64)));
        a1 = __hadd2(a1, u2h2((u32)__shfl_xor((int)h22u(a1), m, 64)));
    }
    if (sub == 0) {
        float2 f0 = __half22float2(a0);
        float2 f1 = __half22float2(a1);
        *(float4*)(out + (size_t)node * NCLASS + 4 * p) =
            make_float4(f0.x, f0.y, f1.x, f1.y);
    }
}

extern "C" void kernel_launch(void* const* d_in, const int* in_sizes, int n_in,
                              void* d_out, int out_size, void* d_ws, size_t ws_size,
                              hipStream_t stream) {
    const float* x  = (const float*)d_in[0];
    const void*  ei = d_in[1];
    const float* ew = (const float*)d_in[2];
    const float* W1 = (const float*)d_in[3];
    const float* W2 = (const float*)d_in[4];
    float* out = (float*)d_out;

    char* ws = (char*)d_ws;
    size_t off = 0;
    auto take = [&](size_t bytes) {
        char* p = ws + off;
        off += (bytes + 511) & ~(size_t)511;
        return p;
    };
    int*   ghist   = (int*)take(NB * 4);
    int*   bstart  = (int*)take((NB + 1) * 4);
    int*   gcursor = (int*)take(NB * 4);
    int*   row_ptr = (int*)take((size_t)(N_NODES + 1) * 4);
    int2*  ebuf    = (int2*)take((size_t)N_EDGES * 8);
    int2*  ebuf2   = (int2*)take((size_t)N_EDGES * 8);
    u32*   xwb     = (u32*)take((size_t)N_NODES * (NHID / 2) * 4);   // f16 packed
    u32*   hb      = (u32*)take((size_t)N_NODES * (NHID / 2) * 4);   // f16 packed
    u32*   hwb     = (u32*)take((size_t)N_NODES * (NCLASS / 2) * 4); // f16 packed

    hipMemsetAsync(ghist, 0, NB * 4, stream);
    mega1_kernel<<<GEMM_BLOCKS + HIST_BLOCKS, 256, 0, stream>>>(x, W1, xwb, ei, ghist);
    scanA_kernel<<<1, NB, 0, stream>>>(ghist, bstart, gcursor);
    fillA_kernel<<<FILL_BLOCKS, 256, 0, stream>>>(ei, ew, gcursor, ebuf);
    sortB_kernel<<<NB, 256, 0, stream>>>(ebuf, bstart, ebuf2, row_ptr);

    agg1_kernel<<<(N_NODES * 64 + 255) / 256, 256, 0, stream>>>(xwb, row_ptr, ebuf2, hb);
    gemm2_kernel<<<GEMM_BLOCKS, 256, 0, stream>>>(hb, W2, hwb);
    agg2_kernel<<<(N_NODES * 64 + 255) / 256, 256, 0, stream>>>(hwb, row_ptr, ebuf2, out);
}

// Round 12
// 139.426 us; speedup vs baseline: 1.3820x; 1.1247x over previous
//
#include <hip/hip_runtime.h>
#include <hip/hip_fp16.h>

#define N_NODES 100000
#define N_EDGES 1600000
#define NFEAT 128
#define NHID 64
#define NCLASS 16

#define NPB 98                     // dst-nodes per bucket
#define NB 1024                    // ceil(100000 / 98) = 1021 -> pad to 1024
#define HIST_EPT 16
#define HIST_BLOCKS ((N_EDGES + 256 * HIST_EPT - 1) / (256 * HIST_EPT))  // 391
#define FILL_EPT 16
#define FILL_BLOCKS ((N_EDGES + 256 * FILL_EPT - 1) / (256 * FILL_EPT))  // 391
#define NTILES ((N_NODES + 15) / 16)            // 6250
#define GEMM_BLOCKS ((NTILES + 3) / 4)          // 1563

typedef unsigned int u32;
typedef __attribute__((ext_vector_type(8))) _Float16 f16x8;
typedef __attribute__((ext_vector_type(4))) float f32x4;

__device__ __forceinline__ __half2 u2h2(u32 u) { __half2 h; __builtin_memcpy(&h, &u, 4); return h; }
__device__ __forceinline__ u32 h22u(__half2 h) { u32 u; __builtin_memcpy(&u, &h, 4); return u; }
__device__ __forceinline__ u32 pack_h16(float a, float b) { return h22u(__floats2half2_rn(a, b)); }

// per-block edge-index dtype detection: odd u32 of first 64 int64 slots are all
// zero iff data is int64 (node ids < 2^31).
__device__ __forceinline__ int detect_i32(const void* ei) {
    u32 v = ((const u32*)ei)[2 * (threadIdx.x & 63) + 1];
    return (__ballot(v != 0) != 0ULL) ? 1 : 0;  // 1 => int32 data
}

__device__ __forceinline__ int load_idx(const void* ei, int flag, size_t pos) {
    return flag ? ((const int*)ei)[pos] : (int)((const long long*)ei)[pos];
}

// ---------- mega1: gemm1 (MFMA f16) blocks first, then histA blocks ----------
__global__ __launch_bounds__(256) void mega1_kernel(const float* __restrict__ X,
                                                    const float* __restrict__ W,
                                                    u32* __restrict__ Y,
                                                    const void* __restrict__ ei,
                                                    int* __restrict__ ghist) {
    __shared__ float Wsh[NFEAT * NHID];  // 32 KB (hist path reuses as int cnt[NB])
    int t = threadIdx.x;
    if (blockIdx.x < GEMM_BLOCKS) {
        for (int i = t; i < NFEAT * NHID; i += 256) Wsh[i] = W[i];
        __syncthreads();
        int wid = t >> 6;
        int lane = t & 63;
        int r = lane & 15, g = lane >> 4;
        int m0 = (blockIdx.x * 4 + wid) * 16;
        if (m0 >= N_NODES) return;

        f16x8 af[4][4];  // [ntile][ktile]
#pragma unroll
        for (int nt = 0; nt < 4; ++nt)
#pragma unroll
            for (int kt = 0; kt < 4; ++kt)
#pragma unroll
                for (int j = 0; j < 8; ++j)
                    af[nt][kt][j] = (_Float16)Wsh[(kt * 32 + g * 8 + j) * NHID + nt * 16 + r];

        const float* xr = X + (size_t)(m0 + r) * NFEAT + g * 8;
        f16x8 bfr[4];
#pragma unroll
        for (int kt = 0; kt < 4; ++kt) {
            float4 v0 = *(const float4*)(xr + kt * 32);
            float4 v1 = *(const float4*)(xr + kt * 32 + 4);
            bfr[kt][0] = (_Float16)v0.x; bfr[kt][1] = (_Float16)v0.y;
            bfr[kt][2] = (_Float16)v0.z; bfr[kt][3] = (_Float16)v0.w;
            bfr[kt][4] = (_Float16)v1.x; bfr[kt][5] = (_Float16)v1.y;
            bfr[kt][6] = (_Float16)v1.z; bfr[kt][7] = (_Float16)v1.w;
        }

        u32* yr = Y + (size_t)(m0 + r) * (NHID / 2);
#pragma unroll
        for (int nt = 0; nt < 4; ++nt) {
            f32x4 acc = {0.f, 0.f, 0.f, 0.f};
#pragma unroll
            for (int kt = 0; kt < 4; ++kt)
                acc = __builtin_amdgcn_mfma_f32_16x16x32_f16(af[nt][kt], bfr[kt], acc, 0, 0, 0);
            uint2 o;
            o.x = pack_h16(acc[0], acc[1]);
            o.y = pack_h16(acc[2], acc[3]);
            *(uint2*)(yr + nt * 8 + g * 2) = o;
        }
    } else {
        int* cnt = (int*)Wsh;
        int bid = blockIdx.x - GEMM_BLOCKS;
#pragma unroll
        for (int k = 0; k < NB / 256; ++k) cnt[t + k * 256] = 0;
        __syncthreads();
        int f = detect_i32(ei);
        int base = bid * 256 * HIST_EPT;
#pragma unroll
        for (int k = 0; k < HIST_EPT; ++k) {
            int e = base + k * 256 + t;
            if (e < N_EDGES) {
                int d = load_idx(ei, f, (size_t)N_EDGES + e);
                atomicAdd(&cnt[d / NPB], 1);
            }
        }
        __syncthreads();
#pragma unroll
        for (int k = 0; k < NB / 256; ++k)
            if (cnt[t + k * 256] > 0) atomicAdd(&ghist[t + k * 256], cnt[t + k * 256]);
    }
}

// single-block scan of NB bucket counts -> bstart (exclusive) + gcursor
__global__ __launch_bounds__(1024) void scanA_kernel(const int* __restrict__ ghist,
                                                     int* __restrict__ bstart,
                                                     int* __restrict__ gcursor) {
    __shared__ int lds[NB];
    int t = threadIdx.x;
    int own = ghist[t];
    lds[t] = own;
    __syncthreads();
    for (int off = 1; off < NB; off <<= 1) {
        int v = (t >= off) ? lds[t - off] : 0;
        __syncthreads();
        lds[t] += v;
        __syncthreads();
    }
    int excl = lds[t] - own;
    bstart[t] = excl;
    if (t == NB - 1) bstart[NB] = lds[NB - 1];
    gcursor[t] = excl;
}

// block-privatized bin scatter: {src | dstl<<20, w} into bucket-contiguous ebuf
// EPT=16 -> ~4 consecutive ranks per (block,bucket) -> 32B write runs
__global__ __launch_bounds__(256) void fillA_kernel(const void* __restrict__ ei,
                                                    const float* __restrict__ ew,
                                                    int* __restrict__ gcursor,
                                                    int2* __restrict__ ebuf) {
    __shared__ int cnt[NB];
    __shared__ int base[NB];
    int t = threadIdx.x;
#pragma unroll
    for (int k = 0; k < NB / 256; ++k) cnt[t + k * 256] = 0;
    __syncthreads();
    int f = detect_i32(ei);
    int eb = blockIdx.x * 256 * FILL_EPT;
    int src[FILL_EPT], bin[FILL_EPT], rank[FILL_EPT];
    float w[FILL_EPT];
#pragma unroll
    for (int k = 0; k < FILL_EPT; ++k) {
        int e = eb + k * 256 + t;
        bin[k] = -1;
        if (e < N_EDGES) {
            int s = load_idx(ei, f, (size_t)e);
            int d = load_idx(ei, f, (size_t)N_EDGES + e);
            int b = d / NPB;
            src[k] = s | ((d - b * NPB) << 20);
            w[k] = ew[e];
            bin[k] = b;
            rank[k] = atomicAdd(&cnt[b], 1);
        }
    }
    __syncthreads();
#pragma unroll
    for (int k = 0; k < NB / 256; ++k)
        if (cnt[t + k * 256] > 0) base[t + k * 256] = atomicAdd(&gcursor[t + k * 256], cnt[t + k * 256]);
    __syncthreads();
#pragma unroll
    for (int k = 0; k < FILL_EPT; ++k) {
        if (bin[k] >= 0) {
            int pos = base[bin[k]] + rank[k];
            ebuf[pos] = make_int2(src[k], __float_as_int(w[k]));
        }
    }
}

// per-bucket counting sort -> exact CSR (ebuf2) + row_ptr
__global__ __launch_bounds__(256) void sortB_kernel(const int2* __restrict__ ebuf,
                                                    const int* __restrict__ bstart,
                                                    int2* __restrict__ ebuf2,
                                                    int* __restrict__ row_ptr) {
    __shared__ int cnt[NPB];
    __shared__ int sc[256];
    __shared__ int cur[NPB];
    int t = threadIdx.x, b = blockIdx.x;
    if (t < NPB) cnt[t] = 0;
    __syncthreads();
    int start = bstart[b], end = bstart[b + 1];
    for (int i = start + t; i < end; i += 256) {
        int dl = ((u32)ebuf[i].x) >> 20;
        atomicAdd(&cnt[dl], 1);
    }
    __syncthreads();
    int own = (t < NPB) ? cnt[t] : 0;
    sc[t] = own;
    __syncthreads();
    for (int off = 1; off < 256; off <<= 1) {
        int v = (t >= off) ? sc[t - off] : 0;
        __syncthreads();
        sc[t] += v;
        __syncthreads();
    }
    int excl = sc[t] - own;
    if (t < NPB) {
        cur[t] = excl;
        int node = b * NPB + t;
        if (node < N_NODES) row_ptr[node] = start + excl;
    }
    if (b == 0 && t == 0) row_ptr[N_NODES] = N_EDGES;
    __syncthreads();
    for (int i = start + t; i < end; i += 256) {
        int2 p = ebuf[i];
        int dl = ((u32)p.x) >> 20;
        int pos = start + atomicAdd(&cur[dl], 1);
        ebuf2[pos] = make_int2(p.x & 0xFFFFF, p.y);
    }
}

// ---------- gemm2 via MFMA f16: D = W2^T x h^T; B-frags load packed-f16 h ----------
__global__ __launch_bounds__(256) void gemm2_kernel(const u32* __restrict__ Hb,
                                                    const float* __restrict__ W,
                                                    u32* __restrict__ Y) {
    __shared__ float Wsh[NHID * NCLASS];  // 4 KB
    int t = threadIdx.x;
    for (int i = t; i < NHID * NCLASS; i += 256) Wsh[i] = W[i];
    __syncthreads();
    int wid = t >> 6;
    int lane = t & 63;
    int r = lane & 15, g = lane >> 4;
    int m0 = (blockIdx.x * 4 + wid) * 16;
    if (m0 >= N_NODES) return;

    f16x8 af[2];
#pragma unroll
    for (int kt = 0; kt < 2; ++kt)
#pragma unroll
        for (int j = 0; j < 8; ++j)
            af[kt][j] = (_Float16)Wsh[(kt * 32 + g * 8 + j) * NCLASS + r];

    const u32* hr = Hb + (size_t)(m0 + r) * (NHID / 2) + g * 4;
    union { uint4 u; f16x8 h; } b0, b1;
    b0.u = *(const uint4*)(hr + 0);
    b1.u = *(const uint4*)(hr + 16);

    f32x4 acc = {0.f, 0.f, 0.f, 0.f};
    acc = __builtin_amdgcn_mfma_f32_16x16x32_f16(af[0], b0.h, acc, 0, 0, 0);
    acc = __builtin_amdgcn_mfma_f32_16x16x32_f16(af[1], b1.h, acc, 0, 0, 0);

    u32* yr = Y + (size_t)(m0 + r) * (NCLASS / 2);
    uint2 o;
    o.x = pack_h16(acc[0], acc[1]);
    o.y = pack_h16(acc[2], acc[3]);
    *(uint2*)(yr + g * 2) = o;
}

// ---------- CSR aggregation with packed-f16 math ----------
// Layer 1: one wave per node; lane = sub*8+p (8 subs); lane gathers uint4
// (8 feats as 4 half2) -> half the instructions/edge of the uint2 shape;
// 2-deep masked unroll -> 16 gathers in flight; butterfly over masks 8,16,32.
__global__ __launch_bounds__(256) void agg1_kernel(const u32* __restrict__ xwb,
                                                   const int* __restrict__ row_ptr,
                                                   const int2* __restrict__ ep,
                                                   u32* __restrict__ hb) {
    int t = blockIdx.x * 256 + threadIdx.x;
    int node = t >> 6;
    int lane = t & 63;
    int p = lane & 7;
    int sub = lane >> 3;
    if (node >= N_NODES) return;
    int start = row_ptr[node], end = row_ptr[node + 1];
    int last = end - 1;
    __half2 a0 = u2h2(0), a1 = u2h2(0), a2 = u2h2(0), a3 = u2h2(0);
    __half2 b0 = u2h2(0), b1 = u2h2(0), b2 = u2h2(0), b3 = u2h2(0);
    for (int i = start + sub; i < end; i += 16) {
        int j1 = min(i + 8, last);
        int2 p0 = ep[i];
        int2 p1 = ep[j1];
        uint4 u0 = *(const uint4*)(xwb + (size_t)p0.x * 32 + 4 * p);
        uint4 u1 = *(const uint4*)(xwb + (size_t)p1.x * 32 + 4 * p);
        float w0f = __int_as_float(p0.y);
        float w1f = (i + 8 < end) ? __int_as_float(p1.y) : 0.f;
        __half2 w0 = __half2half2(__float2half(w0f));
        __half2 w1 = __half2half2(__float2half(w1f));
        a0 = __hfma2(u2h2(u0.x), w0, a0); a1 = __hfma2(u2h2(u0.y), w0, a1);
        a2 = __hfma2(u2h2(u0.z), w0, a2); a3 = __hfma2(u2h2(u0.w), w0, a3);
        b0 = __hfma2(u2h2(u1.x), w1, b0); b1 = __hfma2(u2h2(u1.y), w1, b1);
        b2 = __hfma2(u2h2(u1.z), w1, b2); b3 = __hfma2(u2h2(u1.w), w1, b3);
    }
    a0 = __hadd2(a0, b0); a1 = __hadd2(a1, b1);
    a2 = __hadd2(a2, b2); a3 = __hadd2(a3, b3);
#pragma unroll
    for (int m = 8; m <= 32; m <<= 1) {
        a0 = __hadd2(a0, u2h2((u32)__shfl_xor((int)h22u(a0), m, 64)));
        a1 = __hadd2(a1, u2h2((u32)__shfl_xor((int)h22u(a1), m, 64)));
        a2 = __hadd2(a2, u2h2((u32)__shfl_xor((int)h22u(a2), m, 64)));
        a3 = __hadd2(a3, u2h2((u32)__shfl_xor((int)h22u(a3), m, 64)));
    }
    if (sub == 0) {
        float2 f0 = __half22float2(a0);
        float2 f1 = __half22float2(a1);
        float2 f2 = __half22float2(a2);
        float2 f3 = __half22float2(a3);
        uint4 o;
        o.x = pack_h16(fmaxf(f0.x, 0.f), fmaxf(f0.y, 0.f));
        o.y = pack_h16(fmaxf(f1.x, 0.f), fmaxf(f1.y, 0.f));
        o.z = pack_h16(fmaxf(f2.x, 0.f), fmaxf(f2.y, 0.f));
        o.w = pack_h16(fmaxf(f3.x, 0.f), fmaxf(f3.y, 0.f));
        *(uint4*)(hb + (size_t)node * 32 + 4 * p) = o;
    }
}

// Layer 2: one wave per node; lane = sub*2+p (32 subs); lane gathers uint4
// (8 classes); with deg~16 the whole node completes in ONE un-masked pass;
// butterfly masks 2..32; fp32 out.
__global__ __launch_bounds__(256) void agg2_kernel(const u32* __restrict__ hwb,
                                                   const int* __restrict__ row_ptr,
                                                   const int2* __restrict__ ep,
                                                   float* __restrict__ out) {
    int t = blockIdx.x * 256 + threadIdx.x;
    int node = t >> 6;
    int lane = t & 63;
    int p = lane & 1;
    int sub = lane >> 1;
    if (node >= N_NODES) return;
    int start = row_ptr[node], end = row_ptr[node + 1];
    __half2 a0 = u2h2(0), a1 = u2h2(0), a2 = u2h2(0), a3 = u2h2(0);
    for (int i = start + sub; i < end; i += 32) {
        int2 pr = ep[i];
        uint4 u = *(const uint4*)(hwb + (size_t)pr.x * 8 + 4 * p);
        __half2 w = __half2half2(__float2half(__int_as_float(pr.y)));
        a0 = __hfma2(u2h2(u.x), w, a0); a1 = __hfma2(u2h2(u.y), w, a1);
        a2 = __hfma2(u2h2(u.z), w, a2); a3 = __hfma2(u2h2(u.w), w, a3);
    }
#pragma unroll
    for (int m = 2; m <= 32; m <<= 1) {
        a0 = __hadd2(a0, u2h2((u32)__shfl_xor((int)h22u(a0), m, 64)));
        a1 = __hadd2(a1, u2h2((u32)__shfl_xor((int)h22u(a1), m, 64)));
        a2 = __hadd2(a2, u2h2((u32)__shfl_xor((int)h22u(a2), m, 64)));
        a3 = __hadd2(a3, u2h2((u32)__shfl_xor((int)h22u(a3), m, 64)));
    }
    if (sub == 0) {
        float2 f0 = __half22float2(a0);
        float2 f1 = __half22float2(a1);
        float2 f2 = __half22float2(a2);
        float2 f3 = __half22float2(a3);
        float* op = out + (size_t)node * NCLASS + 8 * p;
        *(float4*)(op + 0) = make_float4(f0.x, f0.y, f1.x, f1.y);
        *(float4*)(op + 4) = make_float4(f2.x, f2.y, f3.x, f3.y);
    }
}

extern "C" void kernel_launch(void* const* d_in, const int* in_sizes, int n_in,
                              void* d_out, int out_size, void* d_ws, size_t ws_size,
                              hipStream_t stream) {
    const float* x  = (const float*)d_in[0];
    const void*  ei = d_in[1];
    const float* ew = (const float*)d_in[2];
    const float* W1 = (const float*)d_in[3];
    const float* W2 = (const float*)d_in[4];
    float* out = (float*)d_out;

    char* ws = (char*)d_ws;
    size_t off = 0;
    auto take = [&](size_t bytes) {
        char* p = ws + off;
        off += (bytes + 511) & ~(size_t)511;
        return p;
    };
    int*   ghist   = (int*)take(NB * 4);
    int*   bstart  = (int*)take((NB + 1) * 4);
    int*   gcursor = (int*)take(NB * 4);
    int*   row_ptr = (int*)take((size_t)(N_NODES + 1) * 4);
    int2*  ebuf    = (int2*)take((size_t)N_EDGES * 8);
    int2*  ebuf2   = (int2*)take((size_t)N_EDGES * 8);
    u32*   xwb     = (u32*)take((size_t)N_NODES * (NHID / 2) * 4);   // f16 packed
    u32*   hb      = (u32*)take((size_t)N_NODES * (NHID / 2) * 4);   // f16 packed
    u32*   hwb     = (u32*)take((size_t)N_NODES * (NCLASS / 2) * 4); // f16 packed

    hipMemsetAsync(ghist, 0, NB * 4, stream);
    mega1_kernel<<<GEMM_BLOCKS + HIST_BLOCKS, 256, 0, stream>>>(x, W1, xwb, ei, ghist);
    scanA_kernel<<<1, NB, 0, stream>>>(ghist, bstart, gcursor);
    fillA_kernel<<<FILL_BLOCKS, 256, 0, stream>>>(ei, ew, gcursor, ebuf);
    sortB_kernel<<<NB, 256, 0, stream>>>(ebuf, bstart, ebuf2, row_ptr);

    agg1_kernel<<<(N_NODES * 64 + 255) / 256, 256, 0, stream>>>(xwb, row_ptr, ebuf2, hb);
    gemm2_kernel<<<GEMM_BLOCKS, 256, 0, stream>>>(hb, W2, hwb);
    agg2_kernel<<<(N_NODES * 64 + 255) / 256, 256, 0, stream>>>(hwb, row_ptr, ebuf2, out);
}